// Round 4
// baseline (384.319 us; speedup 1.0000x reference)
//
#include <hip/hip_runtime.h>
#include <hip/hip_bf16.h>

// QLSTMClassifier: Embedding -> QLSTM (closed-form quantum layer) -> Linear -> log_softmax
// S=256 (batch==seq), E=1024, H=10, V=50257, T=50.
//
//  k_wt   : Wg x-part -> Bfg: bf16 B-fragments in MFMA B-operand layout.
//  k_gemm : zs[b][t][40] = emb[idx[t*256+b]] @ W via mfma_f32_16x16x32_bf16.
//           v2: wave stages its 16 gathered rows into LDS in K-quarters with
//           1KB-contiguous per-row loads (DRAM-friendly), MFMA reads frags from
//           LDS. Wave-local LDS strip -> zero barriers.
//  k_rnn  : per-b recurrence. 2 waves/block: producer streams z into LDS ring;
//           consumer runs the serial chain (DPP scans + bpermute gathers).
//  k_head : logits = hx @ W_out + b_out; log_softmax. Thread per row.
//
// ws (floats): Bfg[24576 eq] | zs[256*256*40] | outs[65536*10]  (~13.3 MB)

#define E_DIM 1024
#define H_DIM 10
#define NC 40
#define EHS 10340      // (E+H)*H per-gate Wg stride
#define ALD 264        // LDS row stride in shorts (528 B): structural-only bank use

typedef __attribute__((ext_vector_type(8))) short bf16x8;
typedef __attribute__((ext_vector_type(4))) float f32x4;

__device__ __forceinline__ unsigned short f2bf(float f) {
    unsigned u = __float_as_uint(f);
    unsigned r = u + 0x7FFFu + ((u >> 16) & 1u);   // RNE
    return (unsigned short)(r >> 16);
}

// ---------------- kernel 0: Wg -> bf16 B-fragments ----------------
// Bfg[((c*3+nt)*64+lane)*8 + j] = bf16(W[k][nc]), k=c*32+(lane>>4)*8+j, nc=nt*16+(lane&15)
__global__ __launch_bounds__(256) void k_wt(const float* __restrict__ Wg,
                                            unsigned short* __restrict__ Bfg) {
    int i = blockIdx.x * 256 + threadIdx.x;     // < 32*3*64 = 6144
    if (i >= 6144) return;
    int lane = i & 63, nt = (i >> 6) % 3, c = i / 192;
    int kg = lane >> 4, n = lane & 15;
    int nc = nt * 16 + n;
    bf16x8 pk;
#pragma unroll
    for (int j = 0; j < 8; ++j) {
        int k = c * 32 + kg * 8 + j;
        float w = 0.0f;
        if (nc < NC) {
            int g = nc / H_DIM, h = nc % H_DIM;
            w = Wg[g * EHS + k * H_DIM + h];
        }
        pk[j] = (short)f2bf(w);
    }
    *(bf16x8*)(Bfg + (size_t)i * 8) = pk;
}

// ---------------- kernel 1: gathered GEMM via MFMA, LDS-staged rows ----------------
// grid 1024 x block 256 (4 waves). Wave handles rows R0..R0+15 (same t).
// Per K-quarter (256 floats): 16 loads of 1KB contiguous (one per row),
// fp32->bf16, ds_write_b64 into wave-local strip, then 8 MFMA chunks.
__global__ __launch_bounds__(256, 4) void k_gemm(const int* __restrict__ idx,
                                                 const float* __restrict__ emb,
                                                 const unsigned short* __restrict__ Bfg,
                                                 float* __restrict__ zs) {
    __shared__ unsigned short As[4][16 * ALD];   // 33 KB total, 8.4 KB per wave
    const int tid = threadIdx.x;
    const int wave = tid >> 6, lane = tid & 63;
    const int R0 = (blockIdx.x * 4 + wave) * 16;
    const int m = lane & 15, q = lane >> 4;
    unsigned short* myA = &As[wave][0];

    int tok[16];
#pragma unroll
    for (int r = 0; r < 16; ++r) tok[r] = idx[R0 + r];

    f32x4 acc0 = {0.f, 0.f, 0.f, 0.f}, acc1 = acc0, acc2 = acc0;

    for (int kq = 0; kq < 4; ++kq) {
        // ---- stage: 16 rows x 256 floats, 1KB contiguous per load ----
        float4 rv[16];
#pragma unroll
        for (int r = 0; r < 16; ++r)
            rv[r] = *(const float4*)(emb + (size_t)tok[r] * E_DIM + kq * 256 + lane * 4);
#pragma unroll
        for (int r = 0; r < 16; ++r) {
            unsigned lo = ((unsigned)f2bf(rv[r].y) << 16) | f2bf(rv[r].x);
            unsigned hi = ((unsigned)f2bf(rv[r].w) << 16) | f2bf(rv[r].z);
            uint2 pk = {lo, hi};
            *(uint2*)(myA + r * ALD + lane * 4) = pk;   // ds_write_b64
        }
        // ---- compute: 8 chunks of K=32 ----
#pragma unroll
        for (int cc = 0; cc < 8; ++cc) {
            const int c = kq * 8 + cc;
            bf16x8 af = *(const bf16x8*)(myA + m * ALD + cc * 32 + q * 8);  // ds_read_b128
            bf16x8 b0 = *(const bf16x8*)(Bfg + ((size_t)(c * 3 + 0) * 64 + lane) * 8);
            bf16x8 b1 = *(const bf16x8*)(Bfg + ((size_t)(c * 3 + 1) * 64 + lane) * 8);
            bf16x8 b2 = *(const bf16x8*)(Bfg + ((size_t)(c * 3 + 2) * 64 + lane) * 8);
            acc0 = __builtin_amdgcn_mfma_f32_16x16x32_bf16(af, b0, acc0, 0, 0, 0);
            acc1 = __builtin_amdgcn_mfma_f32_16x16x32_bf16(af, b1, acc1, 0, 0, 0);
            acc2 = __builtin_amdgcn_mfma_f32_16x16x32_bf16(af, b2, acc2, 0, 0, 0);
        }
    }

    // C/D layout: col = lane&15, row = (lane>>4)*4 + reg
    const int t = R0 >> 8;
    const int bbase = (R0 & 255) + q * 4;
#pragma unroll
    for (int i = 0; i < 4; ++i) {
        int b = bbase + i;
        size_t o = ((size_t)b * 256 + t) * NC;
        zs[o + m] = acc0[i];
        zs[o + 16 + m] = acc1[i];
        if (m < 8) zs[o + 32 + m] = acc2[i];
    }
}

// ---------------- kernel 2: QLSTM recurrence, producer/consumer ----------------
template <int CTRL>
__device__ __forceinline__ float dpp1(float x) {
    // shifted value; out-of-range lanes keep identity 1.0 (old value, bound_ctrl=false)
    return __int_as_float(__builtin_amdgcn_update_dpp(
        __float_as_int(1.0f), __float_as_int(x), CTRL, 0xF, 0xF, false));
}
#define ROW_SHR(n) (0x110 + (n))
#define ROW_SHL(n) (0x100 + (n))

__device__ __forceinline__ float rdlane(float v, int l) {
    return __int_as_float(__builtin_amdgcn_readlane(__float_as_int(v), l));
}

__global__ __launch_bounds__(128) void k_rnn(const float* __restrict__ zs,
                                             const float* __restrict__ Wg,
                                             const float* __restrict__ bg,
                                             const float* __restrict__ theta,
                                             float* __restrict__ outs) {
    __shared__ float zbuf[2][640];   // 16 steps x 40 per buffer
    const int tid = threadIdx.x;
    const int b = blockIdx.x;

    if (tid >= 64) {
        // ---- producer wave: stream zs[b] 16 steps at a time ----
        const int p = tid - 64;
        const float* src = zs + (size_t)b * 256 * NC;
#pragma unroll
        for (int k = 0; k < 10; ++k) zbuf[0][p + k * 64] = src[p + k * 64];
        __syncthreads();
        for (int blk = 0; blk < 16; ++blk) {
            if (blk + 1 < 16) {
                const float* s2 = src + (blk + 1) * 640;
                float v[10];
#pragma unroll
                for (int k = 0; k < 10; ++k) v[k] = s2[p + k * 64];
#pragma unroll
                for (int k = 0; k < 10; ++k) zbuf[(blk + 1) & 1][p + k * 64] = v[k];
            }
            __syncthreads();
        }
    } else {
        // ---- consumer wave: the serial chain ----
        const int lane = tid;
        const int r = lane >> 4;            // gate 0..3 (f,i,g,o)
        const int h = lane & 15;            // wire; valid < 10
        const int hc = (h < 10) ? h : 9;
        const int cidx = r * 10 + hc;

        float Wh[10];
#pragma unroll
        for (int j = 0; j < 10; ++j) Wh[j] = Wg[r * EHS + (E_DIM + j) * H_DIM + hc];
        const float bias = bg[cidx] + theta[cidx];

        const float kk = (r == 2) ? 2.0f : -1.0f;   // tanh : sigmoid
        const float aa = (r == 2) ? 1.0f : 0.0f;
        const float bb = (r == 2) ? -2.0f : 1.0f;

        float cx = 0.0f, hx = 0.0f;
        __syncthreads();

        for (int blk = 0; blk < 16; ++blk) {
            const float* zb = zbuf[blk & 1];
            float zv = zb[cidx];
#pragma unroll 4
            for (int s = 0; s < 16; ++s) {
                float znext = zb[((s < 15) ? (s + 1) * 40 : s * 40) + cidx];

                // hx[0..9] live on lanes 0..9 -> SGPR broadcasts
                float hv0 = rdlane(hx, 0), hv1 = rdlane(hx, 1), hv2 = rdlane(hx, 2),
                      hv3 = rdlane(hx, 3), hv4 = rdlane(hx, 4), hv5 = rdlane(hx, 5),
                      hv6 = rdlane(hx, 6), hv7 = rdlane(hx, 7), hv8 = rdlane(hx, 8),
                      hv9 = rdlane(hx, 9);
                float d0 = fmaf(hv0, Wh[0], fmaf(hv2, Wh[2],
                           fmaf(hv4, Wh[4], fmaf(hv6, Wh[6], hv8 * Wh[8]))));
                float d1 = fmaf(hv1, Wh[1], fmaf(hv3, Wh[3],
                           fmaf(hv5, Wh[5], fmaf(hv7, Wh[7], hv9 * Wh[9]))));
                float z = (zv + bias) + (d0 + d1);

                float cc = __builtin_amdgcn_cosf(z * 0.15915494309189535f);

                // inclusive prefix product P[h] = prod_{j<=h} c_j
                float pp = cc;
                pp *= dpp1<ROW_SHR(1)>(pp);
                pp *= dpp1<ROW_SHR(2)>(pp);
                pp *= dpp1<ROW_SHR(4)>(pp);
                pp *= dpp1<ROW_SHR(8)>(pp);
                // suffix product (pad lanes h>=10 with identity)
                float ss = (h < 10) ? cc : 1.0f;
                ss *= dpp1<ROW_SHL(1)>(ss);
                ss *= dpp1<ROW_SHL(2)>(ss);
                ss *= dpp1<ROW_SHL(4)>(ss);
                ss *= dpp1<ROW_SHL(8)>(ss);
                float tl = dpp1<ROW_SHL(1)>(ss);     // lane 0 -> prod_{j>=1}
                float qv = (h == 0) ? tl : pp;

                float e = __expf(kk * qv);
                float act = fmaf(bb, __builtin_amdgcn_rcpf(1.0f + e), aa);

                // gather f,i,g,o for wire h (lanes h, 16+h, 32+h, 48+h)
                float fv = __shfl(act, h);
                float iv = __shfl(act, 16 + h);
                float gv = __shfl(act, 32 + h);
                float ov = __shfl(act, 48 + h);

                cx = fmaf(fv, cx, iv * gv);
                float e2 = __expf(2.0f * cx);
                float th = fmaf(-2.0f, __builtin_amdgcn_rcpf(1.0f + e2), 1.0f);
                hx = ov * th;

                int t = blk * 16 + s;
                if (lane < 10) outs[((size_t)t * 256 + b) * H_DIM + lane] = hx;
                zv = znext;
            }
            __syncthreads();
        }
    }
}

// ---------------- kernel 3: hidden2tag + log_softmax, thread per row ----------------
__global__ __launch_bounds__(256) void k_head(const float* __restrict__ outs,
                                              const float* __restrict__ Wo,
                                              const float* __restrict__ bo,
                                              float* __restrict__ out) {
    const size_t row = blockIdx.x * 256 + threadIdx.x;   // < 65536
    float hx[10];
#pragma unroll
    for (int i = 0; i < 5; ++i) {
        float2 v = *(const float2*)&outs[row * H_DIM + 2 * i];
        hx[2 * i] = v.x; hx[2 * i + 1] = v.y;
    }
    float lg[50];
#pragma unroll
    for (int cI = 0; cI < 50; ++cI) {
        float l = bo[cI];
#pragma unroll
        for (int j = 0; j < 10; ++j) l = fmaf(hx[j], Wo[j * 50 + cI], l);
        lg[cI] = l;
    }
    float m = lg[0];
#pragma unroll
    for (int cI = 1; cI < 50; ++cI) m = fmaxf(m, lg[cI]);
    float sum = 0.0f;
#pragma unroll
    for (int cI = 0; cI < 50; ++cI) sum += __expf(lg[cI] - m);
    float lse = m + __logf(sum);
#pragma unroll
    for (int i = 0; i < 25; ++i) {
        float2 v = {lg[2 * i] - lse, lg[2 * i + 1] - lse};
        *(float2*)&out[row * 50 + 2 * i] = v;
    }
}

extern "C" void kernel_launch(void* const* d_in, const int* in_sizes, int n_in,
                              void* d_out, int out_size, void* d_ws, size_t ws_size,
                              hipStream_t stream) {
    const int*   sentence = (const int*)d_in[0];     // (256,256)
    const float* emb      = (const float*)d_in[1];   // (50257,1024)
    const float* Wg       = (const float*)d_in[2];   // (4,1034,10)
    const float* bg       = (const float*)d_in[3];   // (4,10)
    const float* theta    = (const float*)d_in[4];   // (4,10)
    const float* Wo       = (const float*)d_in[5];   // (10,50)
    const float* bo       = (const float*)d_in[6];   // (50,)
    float* out = (float*)d_out;

    float* ws = (float*)d_ws;
    unsigned short* Bfg = (unsigned short*)ws;            // 49152 shorts = 24576 floats
    float* zs   = ws + 24576;                             // 256*256*40
    float* outs = zs + (size_t)256 * 256 * NC;            // 65536*10

    k_wt<<<24, 256, 0, stream>>>(Wg, Bfg);
    k_gemm<<<1024, 256, 0, stream>>>(sentence, emb, Bfg, zs);
    k_rnn<<<256, 128, 0, stream>>>(zs, Wg, bg, theta, outs);
    k_head<<<256, 256, 0, stream>>>(outs, Wo, bo, out);
}